// Round 9
// baseline (2286.634 us; speedup 1.0000x reference)
//
#include <hip/hip_runtime.h>
#include <hip/hip_cooperative_groups.h>
#include <math.h>

namespace cg = cooperative_groups;

// Problem constants (fixed by setup_inputs)
#define NN    4
#define NC    3
#define HID   16
#define CST   19     // NC + HID
#define PV    5
#define PERC  95     // PV * CST
#define MIDC  128
#define HH    128
#define WW    128
#define HW    (HH*WW)          // 16384
#define STEPS 16
#define TPX   256              // pixels per block (2 full image rows)
#define NTHR  1024             // 16 waves
#define KP    104              // p_t row stride (bf16): pad 96 -> 104
#define HT    136              // h_t row stride (bf16): pad 128 -> 136

typedef short  bf16x8 __attribute__((ext_vector_type(8)));
typedef short  bf16x4 __attribute__((ext_vector_type(4)));
typedef float  f32x4v __attribute__((ext_vector_type(4)));

// round-to-nearest-even bf16 (hi part of split)
__device__ __forceinline__ unsigned short f2bf_rtn(float f) {
    unsigned u = __float_as_uint(f);
    u += 0x7FFFu + ((u >> 16) & 1u);
    return (unsigned short)(u >> 16);
}
__device__ __forceinline__ float bf2f(unsigned short h) {
    return __uint_as_float(((unsigned)h) << 16);
}
// full split: a ~= hi + lo, both RTN bf16; representation err ~2^-16 |a|
__device__ __forceinline__ void bfsplit(float a, short& hi, short& lo) {
    unsigned short hb = f2bf_rtn(a);
    hi = (short)hb;
    lo = (short)f2bf_rtn(a - bf2f(hb));
}

// ---------------------------------------------------------------------------
// Persistent cooperative kernel: all 16 NCA steps + init colors + final gate.
// Grid = 256 blocks (1/CU, guaranteed by 148 KB LDS) x 1024 threads (16 waves)
// Per step (R8 body unchanged):
//  phase S: gated state tile (prev tmp, global) -> stile LDS
//  phase A: grouped 3x3 conv -> p_t[px][k] RTN-split bf16 (hi/lo)
//  phase B: mids = W1*p, 4-product split-bf16 MFMA 16x16x32 (96 MFMAs/wave)
//  W2:      h -> h_t bf16 hi pass (8 MFMAs) then lo pass (8 MFMAs)
//  epilogue: C-frag + b2 + residual(stile) -> tmp_out;  grid.sync()
// tmp ping-pong: even steps -> state hidden region (stride 19*HW), odd ->
// d_ws (stride 16*HW).  After the loop: final gate+sigmoid bufB -> state
// hidden, and state colors = x.  Weight tables staged once.
// ---------------------------------------------------------------------------
__global__ __launch_bounds__(NTHR) void nca_persist(
        float* __restrict__ state, float* __restrict__ ws,
        const float* __restrict__ x,
        const float* __restrict__ Wp, const float* __restrict__ bp,
        const float* __restrict__ W1, const float* __restrict__ b1,
        const float* __restrict__ W2, const float* __restrict__ b2) {
    cg::grid_group grid = cg::this_grid();

    const int n       = blockIdx.x >> 6;           // 64 blocks per image
    const int pixbase = (blockIdx.x & 63) * TPX;   // 2-row aligned tile
    const int y0      = pixbase >> 7;              // first of 2 rows
    const int tid     = threadIdx.x;
    const int lane    = tid & 63;
    const int w       = __builtin_amdgcn_readfirstlane(tid >> 6);  // 0..15
    const int wrow    = w >> 2;                    // m-group  (0..3)
    const int wcol    = w & 3;                     // px-group (0..3)
    const int lw      = lane & 15;
    const int g       = lane >> 4;
    const int g8      = g * 8;

    // LDS carve: [p_hi 53248][p_lo 53248][stile 32768][w2tab 8448][b1 512][b2 64]
    __shared__ __align__(16) unsigned char raw[148288];
    short* p_hi  = (short*)raw;                    // [256][KP]
    short* p_lo  = p_hi + 256 * KP;
    short* h_t   = (short*)raw;                    // overlays p after phase B
    float* stile = (float*)(raw + 106496);         // [16][4][128]
    float* w2tab = (float*)(raw + 139264);         // [16][132] padded
    float* b1tab = (float*)(raw + 147712);         // [128]
    float* b2tab = (float*)(raw + 148224);         // [16]

    // ---- stage weight tables (once) ----
#pragma unroll
    for (int i = 0; i < 2; ++i) {
        int idx = i * NTHR + tid;                  // 0..2047
        w2tab[(idx >> 7) * 132 + (idx & 127)] = W2[idx];
    }
    if (tid < MIDC) b1tab[tid] = b1[tid];
    else if (tid < MIDC + HID) b2tab[tid - MIDC] = b2[tid - MIDC];

    float* bufA = state + (size_t)NC * HW;         // hidden region of state
    const long strideA = (long)CST * HW;
    float* bufB = ws;
    const long strideB = (long)HID * HW;

    for (int s = 0; s < STEPS; ++s) {
        const float* tmp_in; long istride;
        float* tmp_out;      long ostride;
        if ((s & 1) == 0) { tmp_in = bufB; istride = strideB;
                            tmp_out = bufA; ostride = strideA; }
        else              { tmp_in = bufA; istride = strideA;
                            tmp_out = bufB; ostride = strideB; }
        const int first = (s == 0) ? 1 : 0;

        // ---- phase S: reconstruct gated state tile rows y0-1..y0+2 ----
        {
            const int u2   = tid & 511;            // r = u2>>7, px = u2&127
            const int half = tid >> 9;             // 0: ch 0..7, 1: ch 8..15
            const int px   = u2 & 127;
            const int yy   = y0 - 1 + (u2 >> 7);
            if (!first && yy >= 0 && yy < HH) {
                const float* tb = tmp_in + (size_t)n * istride;
                const float* c1 = tb + 1 * HW;     // abs channel 4
                const int idx = (yy << 7) + px;
                const bool ym = (yy > 0), yp = (yy < HH - 1);
                const bool xm = (px > 0), xp = (px < WW - 1);
                float mx = c1[idx];
                if (ym)       mx = fmaxf(mx, c1[idx - WW]);
                if (yp)       mx = fmaxf(mx, c1[idx + WW]);
                if (xm)       mx = fmaxf(mx, c1[idx - 1]);
                if (xp)       mx = fmaxf(mx, c1[idx + 1]);
                if (ym && xm) mx = fmaxf(mx, c1[idx - WW - 1]);
                if (ym && xp) mx = fmaxf(mx, c1[idx - WW + 1]);
                if (yp && xm) mx = fmaxf(mx, c1[idx + WW - 1]);
                if (yp && xp) mx = fmaxf(mx, c1[idx + WW + 1]);
                const float alive = (mx > 0.0f) ? 1.0f : 0.0f;
#pragma unroll
                for (int cc = 0; cc < 8; ++cc) {
                    const int c = half * 8 + cc;
                    float v = tb[c * HW + idx] * alive;
                    if (c == 1) v = 1.0f / (1.0f + expf(-v));  // sigmoid ch4
                    stile[c * 512 + u2] = v;
                }
            } else {
#pragma unroll
                for (int cc = 0; cc < 8; ++cc)
                    stile[(half * 8 + cc) * 512 + u2] = 0.0f;
            }
        }

        // ---- W1 A-frags (loop-invariant; compiler may hoist) ----
        bf16x8 ah[2][3], al[2][3];
#pragma unroll
        for (int mt = 0; mt < 2; ++mt) {
            const int m = wrow * 32 + mt * 16 + lw;
#pragma unroll
            for (int ks = 0; ks < 3; ++ks) {
                const int kb = ks * 32 + g8;
#pragma unroll
                for (int j = 0; j < 8; ++j) {
                    const int kk = kb + j;
                    float av = (kk < PERC) ? W1[m * PERC + kk] : 0.0f;
                    short h_, l_;
                    bfsplit(av, h_, l_);
                    ah[mt][ks][j] = h_;
                    al[mt][ks][j] = l_;
                }
            }
        }
        __syncthreads();

        // ---- phase A: grouped 3x3 conv -> p_t RTN-split bf16 ----
        auto conv_site = [&](int u) {
            int c = u >> 8;                // wave-uniform (256 | 1024)
            int p = u & 255;
            int y = y0 + (p >> 7);
            int xc = p & 127;
            const bool xm = (xc > 0), xp = (xc < WW - 1);
            float t00, t01, t02, t10, t11, t12, t20, t21, t22;
            if (c < NC) {                  // immutable color channels from x
                const int gpix = (y << 7) + xc;
                const float* ch = x + ((size_t)n * NC + c) * HW;
                const bool ym = (y > 0), yp = (y < HH - 1);
                t00 = (ym && xm) ? ch[gpix - WW - 1] : 0.0f;
                t01 = ym         ? ch[gpix - WW]     : 0.0f;
                t02 = (ym && xp) ? ch[gpix - WW + 1] : 0.0f;
                t10 = xm         ? ch[gpix - 1]      : 0.0f;
                t11 =              ch[gpix];
                t12 = xp         ? ch[gpix + 1]      : 0.0f;
                t20 = (yp && xm) ? ch[gpix + WW - 1] : 0.0f;
                t21 = yp         ? ch[gpix + WW]     : 0.0f;
                t22 = (yp && xp) ? ch[gpix + WW + 1] : 0.0f;
            } else {                       // hidden channels from stile
                const float* sr = stile + (c - NC) * 512;
                const int b = ((p >> 7) + 1) * 128 + xc;   // row 1 or 2
                t00 = xm ? sr[b - 128 - 1] : 0.0f;
                t01 =      sr[b - 128];
                t02 = xp ? sr[b - 128 + 1] : 0.0f;
                t10 = xm ? sr[b - 1]       : 0.0f;
                t11 =      sr[b];
                t12 = xp ? sr[b + 1]       : 0.0f;
                t20 = xm ? sr[b + 128 - 1] : 0.0f;
                t21 =      sr[b + 128];
                t22 = xp ? sr[b + 128 + 1] : 0.0f;
            }
#pragma unroll
            for (int v = 0; v < PV; ++v) {
                const float* wv = Wp + (c * PV + v) * 9;   // wave-uniform s_load
                float a = bp[c * PV + v];
                a += wv[0] * t00; a += wv[1] * t01; a += wv[2] * t02;
                a += wv[3] * t10; a += wv[4] * t11; a += wv[5] * t12;
                a += wv[6] * t20; a += wv[7] * t21; a += wv[8] * t22;
                const int kidx = c * PV + v;
                short h_, l_;
                bfsplit(a, h_, l_);
                p_hi[p * KP + kidx] = h_;
                p_lo[p * KP + kidx] = l_;
            }
        };
#pragma unroll
        for (int it = 0; it < 4; ++it) conv_site(it * NTHR + tid);  // ch 0..15
        if (tid < 768) conv_site(4 * NTHR + tid);                   // ch 16..18
        if (tid < 256) { p_hi[tid * KP + 95] = 0; p_lo[tid * KP + 95] = 0; }
        __syncthreads();

        // ---- phase B: mids = W1*p, 4-product split-bf16 MFMA ----
        f32x4v acc[2][4];
#pragma unroll
        for (int mt = 0; mt < 2; ++mt)
#pragma unroll
            for (int nt = 0; nt < 4; ++nt)
                acc[mt][nt] = (f32x4v){0.0f, 0.0f, 0.0f, 0.0f};

        const int pxb = wcol * 64;
#pragma unroll
        for (int nt = 0; nt < 4; ++nt) {
#pragma unroll
            for (int ks = 0; ks < 3; ++ks) {
                const short* bp_ = &p_hi[(pxb + nt * 16 + lw) * KP + ks * 32 + g8];
                bf16x8 bh = *(const bf16x8*)bp_;
                bf16x8 bl = *(const bf16x8*)(bp_ + 256 * KP);
                acc[0][nt] = __builtin_amdgcn_mfma_f32_16x16x32_bf16(ah[0][ks], bh, acc[0][nt], 0, 0, 0);
                acc[1][nt] = __builtin_amdgcn_mfma_f32_16x16x32_bf16(ah[1][ks], bh, acc[1][nt], 0, 0, 0);
                acc[0][nt] = __builtin_amdgcn_mfma_f32_16x16x32_bf16(ah[0][ks], bl, acc[0][nt], 0, 0, 0);
                acc[1][nt] = __builtin_amdgcn_mfma_f32_16x16x32_bf16(ah[1][ks], bl, acc[1][nt], 0, 0, 0);
                acc[0][nt] = __builtin_amdgcn_mfma_f32_16x16x32_bf16(al[0][ks], bh, acc[0][nt], 0, 0, 0);
                acc[1][nt] = __builtin_amdgcn_mfma_f32_16x16x32_bf16(al[1][ks], bh, acc[1][nt], 0, 0, 0);
                acc[0][nt] = __builtin_amdgcn_mfma_f32_16x16x32_bf16(al[0][ks], bl, acc[0][nt], 0, 0, 0);
                acc[1][nt] = __builtin_amdgcn_mfma_f32_16x16x32_bf16(al[1][ks], bl, acc[1][nt], 0, 0, 0);
            }
        }

        // h = leakyrelu(acc + b1)   (C layout: m = wrow*32+mt*16+g*4+reg)
#pragma unroll
        for (int mt = 0; mt < 2; ++mt) {
            f32x4v bq = *(const f32x4v*)&b1tab[wrow * 32 + mt * 16 + g * 4];
#pragma unroll
            for (int nt = 0; nt < 4; ++nt)
#pragma unroll
                for (int r = 0; r < 4; ++r) {
                    float v = acc[mt][nt][r] + bq[r];
                    acc[mt][nt][r] = (v >= 0.0f) ? v : 0.2f * v;
                }
        }
        __syncthreads();                           // all p reads done

        // ---- h_t hi pass + W2 A-frags (RTN split) ----
#pragma unroll
        for (int mt = 0; mt < 2; ++mt)
#pragma unroll
            for (int nt = 0; nt < 4; ++nt) {
                const int px = pxb + nt * 16 + lw;
                bf16x4 hv;
#pragma unroll
                for (int r = 0; r < 4; ++r) hv[r] = (short)f2bf_rtn(acc[mt][nt][r]);
                *(bf16x4*)&h_t[px * HT + wrow * 32 + mt * 16 + g * 4] = hv;
            }
        bf16x8 wh[4], wl[4];
#pragma unroll
        for (int ks = 0; ks < 4; ++ks) {
            const float* wp2 = &w2tab[lw * 132 + ks * 32 + g8];
            f32x4v qa = *(const f32x4v*)wp2;
            f32x4v qb = *(const f32x4v*)(wp2 + 4);
#pragma unroll
            for (int j = 0; j < 8; ++j) {
                float av = (j < 4) ? qa[j & 3] : qb[j & 3];
                short h_, l_;
                bfsplit(av, h_, l_);
                wh[ks][j] = h_;
                wl[ks][j] = l_;
            }
        }
        __syncthreads();

        // ---- W2 MFMA pass 1: (Wh + Wl) * h_hi ----
        f32x4v acc2 = (f32x4v){0.0f, 0.0f, 0.0f, 0.0f};
#pragma unroll
        for (int ks = 0; ks < 4; ++ks) {
            bf16x8 bh = *(const bf16x8*)&h_t[(w * 16 + lw) * HT + ks * 32 + g8];
            acc2 = __builtin_amdgcn_mfma_f32_16x16x32_bf16(wh[ks], bh, acc2, 0, 0, 0);
            acc2 = __builtin_amdgcn_mfma_f32_16x16x32_bf16(wl[ks], bh, acc2, 0, 0, 0);
        }
        __syncthreads();                           // pass-1 reads done

        // ---- h_t lo pass ----
#pragma unroll
        for (int mt = 0; mt < 2; ++mt)
#pragma unroll
            for (int nt = 0; nt < 4; ++nt) {
                const int px = pxb + nt * 16 + lw;
                bf16x4 lv;
#pragma unroll
                for (int r = 0; r < 4; ++r) {
                    unsigned short hb = f2bf_rtn(acc[mt][nt][r]);
                    lv[r] = (short)f2bf_rtn(acc[mt][nt][r] - bf2f(hb));
                }
                *(bf16x4*)&h_t[px * HT + wrow * 32 + mt * 16 + g * 4] = lv;
            }
        __syncthreads();

        // ---- W2 MFMA pass 2: (Wh + Wl) * h_lo ----
#pragma unroll
        for (int ks = 0; ks < 4; ++ks) {
            bf16x8 bl = *(const bf16x8*)&h_t[(w * 16 + lw) * HT + ks * 32 + g8];
            acc2 = __builtin_amdgcn_mfma_f32_16x16x32_bf16(wh[ks], bl, acc2, 0, 0, 0);
            acc2 = __builtin_amdgcn_mfma_f32_16x16x32_bf16(wl[ks], bl, acc2, 0, 0, 0);
        }

        // ---- epilogue: + b2 + residual(stile), store tmp_out ----
        {
            const int px = w * 16 + lw;            // wave w owns px-tile w
            const int gp = pixbase + px;
            float* tb = tmp_out + (size_t)n * ostride;
#pragma unroll
            for (int r = 0; r < 4; ++r) {
                const int o = g * 4 + r;           // C row = output channel
                float resid = stile[o * 512 + (1 + (px >> 7)) * 128 + (px & 127)];
                tb[(size_t)o * HW + gp] = acc2[r] + b2tab[o] + resid;
            }
        }

        grid.sync();                               // all tmp_out visible
    }

    // ---- final: gate+sigmoid bufB(T15) -> state hidden; colors = x ----
    {
        const int px   = tid & 255;
        const int cgrp = tid >> 8;                 // 4 channels each
        const int idx  = pixbase + px;
        const int y    = idx >> 7;
        const int xc   = idx & 127;
        const float* tb = bufB + (size_t)n * strideB;
        const float* c1 = tb + 1 * HW;
        const bool ym = (y > 0), yp = (y < HH - 1);
        const bool xm = (xc > 0), xp = (xc < WW - 1);
        float mx = c1[idx];
        if (ym)       mx = fmaxf(mx, c1[idx - WW]);
        if (yp)       mx = fmaxf(mx, c1[idx + WW]);
        if (xm)       mx = fmaxf(mx, c1[idx - 1]);
        if (xp)       mx = fmaxf(mx, c1[idx + 1]);
        if (ym && xm) mx = fmaxf(mx, c1[idx - WW - 1]);
        if (ym && xp) mx = fmaxf(mx, c1[idx - WW + 1]);
        if (yp && xm) mx = fmaxf(mx, c1[idx + WW - 1]);
        if (yp && xp) mx = fmaxf(mx, c1[idx + WW + 1]);
        const float alive = (mx > 0.0f) ? 1.0f : 0.0f;
        float* sb = state + (size_t)n * CST * HW + (size_t)NC * HW + idx;
#pragma unroll
        for (int cc = 0; cc < 4; ++cc) {
            const int c = cgrp * 4 + cc;
            float v = tb[c * HW + idx] * alive;
            if (c == 1) v = 1.0f / (1.0f + expf(-v));  // sigmoid abs ch4
            sb[(size_t)c * HW] = v;
        }
        if (tid < 768) {                           // colors: state ch0..2 = x
            const int c = tid >> 8;
            const int p = tid & 255;
            state[(size_t)n * CST * HW + (size_t)c * HW + pixbase + p] =
                x[((size_t)n * NC + c) * HW + pixbase + p];
        }
    }
}

// ---------------------------------------------------------------------------
extern "C" void kernel_launch(void* const* d_in, const int* in_sizes, int n_in,
                              void* d_out, int out_size, void* d_ws, size_t ws_size,
                              hipStream_t stream) {
    const float* x  = (const float*)d_in[0];
    const float* Wp = (const float*)d_in[1];
    const float* bp = (const float*)d_in[2];
    const float* W1 = (const float*)d_in[3];
    const float* b1 = (const float*)d_in[4];
    const float* W2 = (const float*)d_in[5];
    const float* b2 = (const float*)d_in[6];
    // d_in[7] = steps (device scalar) -- fixed at 16 by setup_inputs

    float* state = (float*)d_out;                 // [4][19][128][128]
    float* ws    = (float*)d_ws;                  // [4][16][128][128] (4 MiB)

    void* args[] = { &state, &ws, &x, &Wp, &bp, &W1, &b1, &W2, &b2 };
    hipLaunchCooperativeKernel((const void*)nca_persist,
                               dim3(NN * HW / TPX), dim3(NTHR),
                               args, 0, stream);
}

// Round 10
// 2282.667 us; speedup vs baseline: 1.0017x; 1.0017x over previous
//
#include <hip/hip_runtime.h>
#include <hip/hip_cooperative_groups.h>
#include <math.h>

namespace cg = cooperative_groups;

// Problem constants (fixed by setup_inputs)
#define NN    4
#define NC    3
#define HID   16
#define CST   19     // NC + HID
#define PV    5
#define PERC  95     // PV * CST
#define MIDC  128
#define HH    128
#define WW    128
#define HW    (HH*WW)          // 16384
#define STEPS 16
#define TPX   256              // pixels per block (2 full image rows)
#define NTHR  1024             // 16 waves
#define KP    104              // p_t row stride (bf16): pad 96 -> 104
#define HT    136              // h_t row stride (bf16): pad 128 -> 136

typedef short  bf16x8 __attribute__((ext_vector_type(8)));
typedef short  bf16x4 __attribute__((ext_vector_type(4)));
typedef float  f32x4v __attribute__((ext_vector_type(4)));

// round-to-nearest-even bf16 (hi part of split)
__device__ __forceinline__ unsigned short f2bf_rtn(float f) {
    unsigned u = __float_as_uint(f);
    u += 0x7FFFu + ((u >> 16) & 1u);
    return (unsigned short)(u >> 16);
}
__device__ __forceinline__ float bf2f(unsigned short h) {
    return __uint_as_float(((unsigned)h) << 16);
}
// full split: a ~= hi + lo, both RTN bf16; representation err ~2^-16 |a|
__device__ __forceinline__ void bfsplit(float a, short& hi, short& lo) {
    unsigned short hb = f2bf_rtn(a);
    hi = (short)hb;
    lo = (short)f2bf_rtn(a - bf2f(hb));
}

// ---------------------------------------------------------------------------
// Persistent cooperative kernel: all 16 NCA steps + init colors + final gate.
// Grid = 256 blocks (1/CU, guaranteed by 148 KB LDS) x 1024 threads (16 waves)
// __launch_bounds__(1024, 4): 4 waves/EU min = the occupancy LDS already pins
// us to; raises the VGPR budget to 128 (R9's default choice of 64 spilled the
// MFMA working set to scratch -> 3 GB/dispatch scratch traffic, 5x slowdown).
// Per step (R8 body unchanged):
//  phase S: gated state tile (prev tmp, global) -> stile LDS
//  phase A: grouped 3x3 conv -> p_t[px][k] RTN-split bf16 (hi/lo)
//  phase B: mids = W1*p, 4-product split-bf16 MFMA 16x16x32 (96 MFMAs/wave)
//  W2:      h -> h_t bf16 hi pass (8 MFMAs) then lo pass (8 MFMAs)
//  epilogue: C-frag + b2 + residual(stile) -> tmp_out;  grid.sync()
// tmp ping-pong: even steps -> state hidden region (stride 19*HW), odd ->
// d_ws (stride 16*HW).  After the loop: final gate+sigmoid bufB -> state
// hidden, and state colors = x.  Weight tables staged once.
// ---------------------------------------------------------------------------
__global__ __launch_bounds__(NTHR, 4) void nca_persist(
        float* __restrict__ state, float* __restrict__ ws,
        const float* __restrict__ x,
        const float* __restrict__ Wp, const float* __restrict__ bp,
        const float* __restrict__ W1, const float* __restrict__ b1,
        const float* __restrict__ W2, const float* __restrict__ b2) {
    cg::grid_group grid = cg::this_grid();

    const int n       = blockIdx.x >> 6;           // 64 blocks per image
    const int pixbase = (blockIdx.x & 63) * TPX;   // 2-row aligned tile
    const int y0      = pixbase >> 7;              // first of 2 rows
    const int tid     = threadIdx.x;
    const int lane    = tid & 63;
    const int w       = __builtin_amdgcn_readfirstlane(tid >> 6);  // 0..15
    const int wrow    = w >> 2;                    // m-group  (0..3)
    const int wcol    = w & 3;                     // px-group (0..3)
    const int lw      = lane & 15;
    const int g       = lane >> 4;
    const int g8      = g * 8;

    // LDS carve: [p_hi 53248][p_lo 53248][stile 32768][w2tab 8448][b1 512][b2 64]
    __shared__ __align__(16) unsigned char raw[148288];
    short* p_hi  = (short*)raw;                    // [256][KP]
    short* p_lo  = p_hi + 256 * KP;
    short* h_t   = (short*)raw;                    // overlays p after phase B
    float* stile = (float*)(raw + 106496);         // [16][4][128]
    float* w2tab = (float*)(raw + 139264);         // [16][132] padded
    float* b1tab = (float*)(raw + 147712);         // [128]
    float* b2tab = (float*)(raw + 148224);         // [16]

    // ---- stage weight tables (once) ----
#pragma unroll
    for (int i = 0; i < 2; ++i) {
        int idx = i * NTHR + tid;                  // 0..2047
        w2tab[(idx >> 7) * 132 + (idx & 127)] = W2[idx];
    }
    if (tid < MIDC) b1tab[tid] = b1[tid];
    else if (tid < MIDC + HID) b2tab[tid - MIDC] = b2[tid - MIDC];

    float* bufA = state + (size_t)NC * HW;         // hidden region of state
    const long strideA = (long)CST * HW;
    float* bufB = ws;
    const long strideB = (long)HID * HW;

    for (int s = 0; s < STEPS; ++s) {
        const float* tmp_in; long istride;
        float* tmp_out;      long ostride;
        if ((s & 1) == 0) { tmp_in = bufB; istride = strideB;
                            tmp_out = bufA; ostride = strideA; }
        else              { tmp_in = bufA; istride = strideA;
                            tmp_out = bufB; ostride = strideB; }
        const int first = (s == 0) ? 1 : 0;

        // ---- phase S: reconstruct gated state tile rows y0-1..y0+2 ----
        {
            const int u2   = tid & 511;            // r = u2>>7, px = u2&127
            const int half = tid >> 9;             // 0: ch 0..7, 1: ch 8..15
            const int px   = u2 & 127;
            const int yy   = y0 - 1 + (u2 >> 7);
            if (!first && yy >= 0 && yy < HH) {
                const float* tb = tmp_in + (size_t)n * istride;
                const float* c1 = tb + 1 * HW;     // abs channel 4
                const int idx = (yy << 7) + px;
                const bool ym = (yy > 0), yp = (yy < HH - 1);
                const bool xm = (px > 0), xp = (px < WW - 1);
                float mx = c1[idx];
                if (ym)       mx = fmaxf(mx, c1[idx - WW]);
                if (yp)       mx = fmaxf(mx, c1[idx + WW]);
                if (xm)       mx = fmaxf(mx, c1[idx - 1]);
                if (xp)       mx = fmaxf(mx, c1[idx + 1]);
                if (ym && xm) mx = fmaxf(mx, c1[idx - WW - 1]);
                if (ym && xp) mx = fmaxf(mx, c1[idx - WW + 1]);
                if (yp && xm) mx = fmaxf(mx, c1[idx + WW - 1]);
                if (yp && xp) mx = fmaxf(mx, c1[idx + WW + 1]);
                const float alive = (mx > 0.0f) ? 1.0f : 0.0f;
#pragma unroll
                for (int cc = 0; cc < 8; ++cc) {
                    const int c = half * 8 + cc;
                    float v = tb[c * HW + idx] * alive;
                    if (c == 1) v = 1.0f / (1.0f + expf(-v));  // sigmoid ch4
                    stile[c * 512 + u2] = v;
                }
            } else {
#pragma unroll
                for (int cc = 0; cc < 8; ++cc)
                    stile[(half * 8 + cc) * 512 + u2] = 0.0f;
            }
        }

        // ---- W1 A-frags (reloaded per step; short live range) ----
        bf16x8 ah[2][3], al[2][3];
#pragma unroll
        for (int mt = 0; mt < 2; ++mt) {
            const int m = wrow * 32 + mt * 16 + lw;
#pragma unroll
            for (int ks = 0; ks < 3; ++ks) {
                const int kb = ks * 32 + g8;
#pragma unroll
                for (int j = 0; j < 8; ++j) {
                    const int kk = kb + j;
                    float av = (kk < PERC) ? W1[m * PERC + kk] : 0.0f;
                    short h_, l_;
                    bfsplit(av, h_, l_);
                    ah[mt][ks][j] = h_;
                    al[mt][ks][j] = l_;
                }
            }
        }
        __syncthreads();

        // ---- phase A: grouped 3x3 conv -> p_t RTN-split bf16 ----
        auto conv_site = [&](int u) {
            int c = u >> 8;                // wave-uniform (256 | 1024)
            int p = u & 255;
            int y = y0 + (p >> 7);
            int xc = p & 127;
            const bool xm = (xc > 0), xp = (xc < WW - 1);
            float t00, t01, t02, t10, t11, t12, t20, t21, t22;
            if (c < NC) {                  // immutable color channels from x
                const int gpix = (y << 7) + xc;
                const float* ch = x + ((size_t)n * NC + c) * HW;
                const bool ym = (y > 0), yp = (y < HH - 1);
                t00 = (ym && xm) ? ch[gpix - WW - 1] : 0.0f;
                t01 = ym         ? ch[gpix - WW]     : 0.0f;
                t02 = (ym && xp) ? ch[gpix - WW + 1] : 0.0f;
                t10 = xm         ? ch[gpix - 1]      : 0.0f;
                t11 =              ch[gpix];
                t12 = xp         ? ch[gpix + 1]      : 0.0f;
                t20 = (yp && xm) ? ch[gpix + WW - 1] : 0.0f;
                t21 = yp         ? ch[gpix + WW]     : 0.0f;
                t22 = (yp && xp) ? ch[gpix + WW + 1] : 0.0f;
            } else {                       // hidden channels from stile
                const float* sr = stile + (c - NC) * 512;
                const int b = ((p >> 7) + 1) * 128 + xc;   // row 1 or 2
                t00 = xm ? sr[b - 128 - 1] : 0.0f;
                t01 =      sr[b - 128];
                t02 = xp ? sr[b - 128 + 1] : 0.0f;
                t10 = xm ? sr[b - 1]       : 0.0f;
                t11 =      sr[b];
                t12 = xp ? sr[b + 1]       : 0.0f;
                t20 = xm ? sr[b + 128 - 1] : 0.0f;
                t21 =      sr[b + 128];
                t22 = xp ? sr[b + 128 + 1] : 0.0f;
            }
#pragma unroll
            for (int v = 0; v < PV; ++v) {
                const float* wv = Wp + (c * PV + v) * 9;   // wave-uniform s_load
                float a = bp[c * PV + v];
                a += wv[0] * t00; a += wv[1] * t01; a += wv[2] * t02;
                a += wv[3] * t10; a += wv[4] * t11; a += wv[5] * t12;
                a += wv[6] * t20; a += wv[7] * t21; a += wv[8] * t22;
                const int kidx = c * PV + v;
                short h_, l_;
                bfsplit(a, h_, l_);
                p_hi[p * KP + kidx] = h_;
                p_lo[p * KP + kidx] = l_;
            }
        };
#pragma unroll
        for (int it = 0; it < 4; ++it) conv_site(it * NTHR + tid);  // ch 0..15
        if (tid < 768) conv_site(4 * NTHR + tid);                   // ch 16..18
        if (tid < 256) { p_hi[tid * KP + 95] = 0; p_lo[tid * KP + 95] = 0; }
        __syncthreads();

        // ---- phase B: mids = W1*p, 4-product split-bf16 MFMA ----
        f32x4v acc[2][4];
#pragma unroll
        for (int mt = 0; mt < 2; ++mt)
#pragma unroll
            for (int nt = 0; nt < 4; ++nt)
                acc[mt][nt] = (f32x4v){0.0f, 0.0f, 0.0f, 0.0f};

        const int pxb = wcol * 64;
#pragma unroll
        for (int nt = 0; nt < 4; ++nt) {
#pragma unroll
            for (int ks = 0; ks < 3; ++ks) {
                const short* bp_ = &p_hi[(pxb + nt * 16 + lw) * KP + ks * 32 + g8];
                bf16x8 bh = *(const bf16x8*)bp_;
                bf16x8 bl = *(const bf16x8*)(bp_ + 256 * KP);
                acc[0][nt] = __builtin_amdgcn_mfma_f32_16x16x32_bf16(ah[0][ks], bh, acc[0][nt], 0, 0, 0);
                acc[1][nt] = __builtin_amdgcn_mfma_f32_16x16x32_bf16(ah[1][ks], bh, acc[1][nt], 0, 0, 0);
                acc[0][nt] = __builtin_amdgcn_mfma_f32_16x16x32_bf16(ah[0][ks], bl, acc[0][nt], 0, 0, 0);
                acc[1][nt] = __builtin_amdgcn_mfma_f32_16x16x32_bf16(ah[1][ks], bl, acc[1][nt], 0, 0, 0);
                acc[0][nt] = __builtin_amdgcn_mfma_f32_16x16x32_bf16(al[0][ks], bh, acc[0][nt], 0, 0, 0);
                acc[1][nt] = __builtin_amdgcn_mfma_f32_16x16x32_bf16(al[1][ks], bh, acc[1][nt], 0, 0, 0);
                acc[0][nt] = __builtin_amdgcn_mfma_f32_16x16x32_bf16(al[0][ks], bl, acc[0][nt], 0, 0, 0);
                acc[1][nt] = __builtin_amdgcn_mfma_f32_16x16x32_bf16(al[1][ks], bl, acc[1][nt], 0, 0, 0);
            }
        }

        // h = leakyrelu(acc + b1)   (C layout: m = wrow*32+mt*16+g*4+reg)
#pragma unroll
        for (int mt = 0; mt < 2; ++mt) {
            f32x4v bq = *(const f32x4v*)&b1tab[wrow * 32 + mt * 16 + g * 4];
#pragma unroll
            for (int nt = 0; nt < 4; ++nt)
#pragma unroll
                for (int r = 0; r < 4; ++r) {
                    float v = acc[mt][nt][r] + bq[r];
                    acc[mt][nt][r] = (v >= 0.0f) ? v : 0.2f * v;
                }
        }
        __syncthreads();                           // all p reads done

        // ---- h_t hi pass + W2 A-frags (RTN split) ----
#pragma unroll
        for (int mt = 0; mt < 2; ++mt)
#pragma unroll
            for (int nt = 0; nt < 4; ++nt) {
                const int px = pxb + nt * 16 + lw;
                bf16x4 hv;
#pragma unroll
                for (int r = 0; r < 4; ++r) hv[r] = (short)f2bf_rtn(acc[mt][nt][r]);
                *(bf16x4*)&h_t[px * HT + wrow * 32 + mt * 16 + g * 4] = hv;
            }
        bf16x8 wh[4], wl[4];
#pragma unroll
        for (int ks = 0; ks < 4; ++ks) {
            const float* wp2 = &w2tab[lw * 132 + ks * 32 + g8];
            f32x4v qa = *(const f32x4v*)wp2;
            f32x4v qb = *(const f32x4v*)(wp2 + 4);
#pragma unroll
            for (int j = 0; j < 8; ++j) {
                float av = (j < 4) ? qa[j & 3] : qb[j & 3];
                short h_, l_;
                bfsplit(av, h_, l_);
                wh[ks][j] = h_;
                wl[ks][j] = l_;
            }
        }
        __syncthreads();

        // ---- W2 MFMA pass 1: (Wh + Wl) * h_hi ----
        f32x4v acc2 = (f32x4v){0.0f, 0.0f, 0.0f, 0.0f};
#pragma unroll
        for (int ks = 0; ks < 4; ++ks) {
            bf16x8 bh = *(const bf16x8*)&h_t[(w * 16 + lw) * HT + ks * 32 + g8];
            acc2 = __builtin_amdgcn_mfma_f32_16x16x32_bf16(wh[ks], bh, acc2, 0, 0, 0);
            acc2 = __builtin_amdgcn_mfma_f32_16x16x32_bf16(wl[ks], bh, acc2, 0, 0, 0);
        }
        __syncthreads();                           // pass-1 reads done

        // ---- h_t lo pass ----
#pragma unroll
        for (int mt = 0; mt < 2; ++mt)
#pragma unroll
            for (int nt = 0; nt < 4; ++nt) {
                const int px = pxb + nt * 16 + lw;
                bf16x4 lv;
#pragma unroll
                for (int r = 0; r < 4; ++r) {
                    unsigned short hb = f2bf_rtn(acc[mt][nt][r]);
                    lv[r] = (short)f2bf_rtn(acc[mt][nt][r] - bf2f(hb));
                }
                *(bf16x4*)&h_t[px * HT + wrow * 32 + mt * 16 + g * 4] = lv;
            }
        __syncthreads();

        // ---- W2 MFMA pass 2: (Wh + Wl) * h_lo ----
#pragma unroll
        for (int ks = 0; ks < 4; ++ks) {
            bf16x8 bl = *(const bf16x8*)&h_t[(w * 16 + lw) * HT + ks * 32 + g8];
            acc2 = __builtin_amdgcn_mfma_f32_16x16x32_bf16(wh[ks], bl, acc2, 0, 0, 0);
            acc2 = __builtin_amdgcn_mfma_f32_16x16x32_bf16(wl[ks], bl, acc2, 0, 0, 0);
        }

        // ---- epilogue: + b2 + residual(stile), store tmp_out ----
        {
            const int px = w * 16 + lw;            // wave w owns px-tile w
            const int gp = pixbase + px;
            float* tb = tmp_out + (size_t)n * ostride;
#pragma unroll
            for (int r = 0; r < 4; ++r) {
                const int o = g * 4 + r;           // C row = output channel
                float resid = stile[o * 512 + (1 + (px >> 7)) * 128 + (px & 127)];
                tb[(size_t)o * HW + gp] = acc2[r] + b2tab[o] + resid;
            }
        }

        grid.sync();                               // all tmp_out visible
    }

    // ---- final: gate+sigmoid bufB(T15) -> state hidden; colors = x ----
    {
        const int px   = tid & 255;
        const int cgrp = tid >> 8;                 // 4 channels each
        const int idx  = pixbase + px;
        const int y    = idx >> 7;
        const int xc   = idx & 127;
        const float* tb = bufB + (size_t)n * strideB;
        const float* c1 = tb + 1 * HW;
        const bool ym = (y > 0), yp = (y < HH - 1);
        const bool xm = (xc > 0), xp = (xc < WW - 1);
        float mx = c1[idx];
        if (ym)       mx = fmaxf(mx, c1[idx - WW]);
        if (yp)       mx = fmaxf(mx, c1[idx + WW]);
        if (xm)       mx = fmaxf(mx, c1[idx - 1]);
        if (xp)       mx = fmaxf(mx, c1[idx + 1]);
        if (ym && xm) mx = fmaxf(mx, c1[idx - WW - 1]);
        if (ym && xp) mx = fmaxf(mx, c1[idx - WW + 1]);
        if (yp && xm) mx = fmaxf(mx, c1[idx + WW - 1]);
        if (yp && xp) mx = fmaxf(mx, c1[idx + WW + 1]);
        const float alive = (mx > 0.0f) ? 1.0f : 0.0f;
        float* sb = state + (size_t)n * CST * HW + (size_t)NC * HW + idx;
#pragma unroll
        for (int cc = 0; cc < 4; ++cc) {
            const int c = cgrp * 4 + cc;
            float v = tb[c * HW + idx] * alive;
            if (c == 1) v = 1.0f / (1.0f + expf(-v));  // sigmoid abs ch4
            sb[(size_t)c * HW] = v;
        }
        if (tid < 768) {                           // colors: state ch0..2 = x
            const int c = tid >> 8;
            const int p = tid & 255;
            state[(size_t)n * CST * HW + (size_t)c * HW + pixbase + p] =
                x[((size_t)n * NC + c) * HW + pixbase + p];
        }
    }
}

// ---------------------------------------------------------------------------
extern "C" void kernel_launch(void* const* d_in, const int* in_sizes, int n_in,
                              void* d_out, int out_size, void* d_ws, size_t ws_size,
                              hipStream_t stream) {
    const float* x  = (const float*)d_in[0];
    const float* Wp = (const float*)d_in[1];
    const float* bp = (const float*)d_in[2];
    const float* W1 = (const float*)d_in[3];
    const float* b1 = (const float*)d_in[4];
    const float* W2 = (const float*)d_in[5];
    const float* b2 = (const float*)d_in[6];
    // d_in[7] = steps (device scalar) -- fixed at 16 by setup_inputs

    float* state = (float*)d_out;                 // [4][19][128][128]
    float* ws    = (float*)d_ws;                  // [4][16][128][128] (4 MiB)

    void* args[] = { &state, &ws, &x, &Wp, &bp, &W1, &b1, &W2, &b2 };
    hipLaunchCooperativeKernel((const void*)nca_persist,
                               dim3(NN * HW / TPX), dim3(NTHR),
                               args, 0, stream);
}

// Round 11
// 365.901 us; speedup vs baseline: 6.2493x; 6.2385x over previous
//
#include <hip/hip_runtime.h>
#include <math.h>

// Problem constants (fixed by setup_inputs)
#define NN    4
#define NC    3
#define HID   16
#define CST   19     // NC + HID
#define PV    5
#define PERC  95     // PV * CST
#define MIDC  128
#define HH    128
#define WW    128
#define HW    (HH*WW)          // 16384
#define STEPS 16
#define TPX   256              // pixels per block (2 full image rows)
#define NTHR  1024             // 16 waves
#define KP    104              // p_t row stride (bf16): pad 96 -> 104
#define HT    136              // h_t row stride (bf16): pad 128 -> 136
#define W1F_N 24576            // W1 frag shorts: 4 wrow x 12 chunks x 64 lanes x 8
#define W2F_N 4096             // W2 frag shorts: 8 chunks x 64 lanes x 8

typedef short  bf16x8 __attribute__((ext_vector_type(8)));
typedef short  bf16x4 __attribute__((ext_vector_type(4)));
typedef float  f32x4v __attribute__((ext_vector_type(4)));

// round-to-nearest-even bf16 (hi part of split)
__device__ __forceinline__ unsigned short f2bf_rtn(float f) {
    unsigned u = __float_as_uint(f);
    u += 0x7FFFu + ((u >> 16) & 1u);
    return (unsigned short)(u >> 16);
}
__device__ __forceinline__ float bf2f(unsigned short h) {
    return __uint_as_float(((unsigned)h) << 16);
}
// full split: a ~= hi + lo, both RTN bf16; representation err ~2^-16 |a|
__device__ __forceinline__ void bfsplit(float a, short& hi, short& lo) {
    unsigned short hb = f2bf_rtn(a);
    hi = (short)hb;
    lo = (short)f2bf_rtn(a - bf2f(hb));
}

// ---------------------------------------------------------------------------
// one-off weight prep: split-bf16 MFMA fragments for W1 and W2, written into
// the image-0 color plane of state (57 KB of 196 KB; colors are dead during
// the steps -- conv reads x -- and are restored by nca_step2 at the end).
// w1f layout: e = ((wrow*12 + ch)*64 + lane)*8 + j, ch = (mt*3+ks)*2 + hl
//   value = split(W1[(wrow*32+mt*16+lw) * 95 + ks*32+g*8+j]), 0 for k>=95
// w2f layout: e = ((ks*2+hl)*64 + lane)*8 + j
//   value = split(W2[lw*128 + ks*32+g*8+j])
// ---------------------------------------------------------------------------
__global__ __launch_bounds__(1024) void nca_wprep(
        short* __restrict__ wf,
        const float* __restrict__ W1, const float* __restrict__ W2) {
    const int tid = threadIdx.x;
    for (int e = tid; e < W1F_N; e += 1024) {
        int j = e & 7, lane = (e >> 3) & 63, q = e >> 9;   // q = wrow*12+ch
        int ch = q % 12, wrow = q / 12;
        int hl = ch & 1, t = ch >> 1, ks = t % 3, mt = t / 3;
        int lw = lane & 15, g = lane >> 4;
        int m  = wrow * 32 + mt * 16 + lw;
        int kk = ks * 32 + g * 8 + j;
        float av = (kk < PERC) ? W1[m * PERC + kk] : 0.0f;
        short hi, lo; bfsplit(av, hi, lo);
        wf[e] = hl ? lo : hi;
    }
    for (int e = tid; e < W2F_N; e += 1024) {
        int j = e & 7, lane = (e >> 3) & 63, q = e >> 9;   // q = ks*2+hl
        int hl = q & 1, ks = q >> 1;
        int lw = lane & 15, g = lane >> 4;
        float av = W2[lw * MIDC + ks * 32 + g * 8 + j];
        short hi, lo; bfsplit(av, hi, lo);
        wf[W1F_N + e] = hl ? lo : hi;
    }
}

// ---------------------------------------------------------------------------
// fused step kernel (R8 body + precomputed weight frags).
// Block = 1024 threads (16 waves = 4 wrow x 4 wcol), tile = 256 px (2 rows).
//  phase S: gated state tile (prev tmp) -> stile LDS
//  phase A: grouped 3x3 conv -> p_t[px][k] RTN-split bf16 (hi/lo)
//  phase B: mids = W1*p, 4-product split-bf16 MFMA 16x16x32 (96 MFMAs/wave);
//           W1 frags = 12 coalesced 16B loads from wscr (was 48 scattered
//           dword + ~300 VALU split per lane per step)
//  W2:      h -> h_t bf16 hi pass (8 MFMAs) then lo pass (8 MFMAs);
//           W2 frags = 8 coalesced 16B loads (w2tab LDS staging deleted)
//  epilogue: C-frag + b2 + residual(stile) -> tmp_out.
// tmp ping-pong: even steps -> state hidden region (stride 19*HW), odd ->
// d_ws (stride 16*HW); reads always from the other buffer (prev launch).
// ---------------------------------------------------------------------------
__global__ __launch_bounds__(NTHR) void nca_fused(
        const float* __restrict__ tmp_in,  long istride,
        float* __restrict__ tmp_out,       long ostride,
        const float* __restrict__ x,
        const short* __restrict__ wscr,
        const float* __restrict__ Wp, const float* __restrict__ bp,
        const float* __restrict__ b1, const float* __restrict__ b2,
        int first) {
    const int n       = blockIdx.x >> 6;           // 64 blocks per image
    const int pixbase = (blockIdx.x & 63) * TPX;   // 2-row aligned tile
    const int y0      = pixbase >> 7;              // first of 2 rows
    const int tid     = threadIdx.x;
    const int lane    = tid & 63;
    const int w       = __builtin_amdgcn_readfirstlane(tid >> 6);  // 0..15
    const int wrow    = w >> 2;                    // m-group  (0..3)
    const int wcol    = w & 3;                     // px-group (0..3)
    const int lw      = lane & 15;
    const int g       = lane >> 4;
    const int g8      = g * 8;

    // LDS carve: [p_hi 53248][p_lo 53248][stile 32768][b1 512][b2 64]
    __shared__ __align__(16) unsigned char raw[139840];
    short* p_hi  = (short*)raw;                    // [256][KP]
    short* p_lo  = p_hi + 256 * KP;
    short* h_t   = (short*)raw;                    // overlays p after phase B
    float* stile = (float*)(raw + 106496);         // [16][4][128]
    float* b1tab = (float*)(raw + 139264);         // [128]
    float* b2tab = (float*)(raw + 139776);         // [16]

    if (tid < MIDC) b1tab[tid] = b1[tid];
    else if (tid < MIDC + HID) b2tab[tid - MIDC] = b2[tid - MIDC];

    // ---- phase S: reconstruct gated state tile rows y0-1..y0+2 ----
    {
        const int u2   = tid & 511;                // r = u2>>7, px = u2&127
        const int half = tid >> 9;                 // 0: ch 0..7, 1: ch 8..15
        const int px   = u2 & 127;
        const int yy   = y0 - 1 + (u2 >> 7);
        if (!first && yy >= 0 && yy < HH) {
            const float* tb = tmp_in + (size_t)n * istride;
            const float* c1 = tb + 1 * HW;         // abs channel 4
            const int idx = (yy << 7) + px;
            const bool ym = (yy > 0), yp = (yy < HH - 1);
            const bool xm = (px > 0), xp = (px < WW - 1);
            float mx = c1[idx];
            if (ym)       mx = fmaxf(mx, c1[idx - WW]);
            if (yp)       mx = fmaxf(mx, c1[idx + WW]);
            if (xm)       mx = fmaxf(mx, c1[idx - 1]);
            if (xp)       mx = fmaxf(mx, c1[idx + 1]);
            if (ym && xm) mx = fmaxf(mx, c1[idx - WW - 1]);
            if (ym && xp) mx = fmaxf(mx, c1[idx - WW + 1]);
            if (yp && xm) mx = fmaxf(mx, c1[idx + WW - 1]);
            if (yp && xp) mx = fmaxf(mx, c1[idx + WW + 1]);
            const float alive = (mx > 0.0f) ? 1.0f : 0.0f;
#pragma unroll
            for (int cc = 0; cc < 8; ++cc) {
                const int c = half * 8 + cc;
                float v = tb[c * HW + idx] * alive;
                if (c == 1) v = 1.0f / (1.0f + expf(-v));  // sigmoid abs ch4
                stile[c * 512 + u2] = v;
            }
        } else {
#pragma unroll
            for (int cc = 0; cc < 8; ++cc)
                stile[(half * 8 + cc) * 512 + u2] = 0.0f;
        }
    }

    // ---- W1 A-frags: 12 coalesced 16B loads from precomputed scratch ----
    bf16x8 ah[2][3], al[2][3];
#pragma unroll
    for (int mt = 0; mt < 2; ++mt)
#pragma unroll
        for (int ks = 0; ks < 3; ++ks) {
            const int base = ((wrow * 12 + ((mt * 3 + ks) << 1)) * 64 + lane) * 8;
            ah[mt][ks] = *(const bf16x8*)&wscr[base];
            al[mt][ks] = *(const bf16x8*)&wscr[base + 512];   // hl=1 chunk
        }
    __syncthreads();

    // ---- phase A: grouped 3x3 conv -> p_t RTN-split bf16 ----
    auto conv_site = [&](int u) {
        int c = u >> 8;                // wave-uniform (256 | 1024)
        int p = u & 255;
        int y = y0 + (p >> 7);
        int xc = p & 127;
        const bool xm = (xc > 0), xp = (xc < WW - 1);
        float t00, t01, t02, t10, t11, t12, t20, t21, t22;
        if (c < NC) {                  // immutable color channels from x
            const int gpix = (y << 7) + xc;
            const float* ch = x + ((size_t)n * NC + c) * HW;
            const bool ym = (y > 0), yp = (y < HH - 1);
            t00 = (ym && xm) ? ch[gpix - WW - 1] : 0.0f;
            t01 = ym         ? ch[gpix - WW]     : 0.0f;
            t02 = (ym && xp) ? ch[gpix - WW + 1] : 0.0f;
            t10 = xm         ? ch[gpix - 1]      : 0.0f;
            t11 =              ch[gpix];
            t12 = xp         ? ch[gpix + 1]      : 0.0f;
            t20 = (yp && xm) ? ch[gpix + WW - 1] : 0.0f;
            t21 = yp         ? ch[gpix + WW]     : 0.0f;
            t22 = (yp && xp) ? ch[gpix + WW + 1] : 0.0f;
        } else {                       // hidden channels from stile
            const float* sr = stile + (c - NC) * 512;
            const int b = ((p >> 7) + 1) * 128 + xc;   // row 1 or 2
            t00 = xm ? sr[b - 128 - 1] : 0.0f;
            t01 =      sr[b - 128];
            t02 = xp ? sr[b - 128 + 1] : 0.0f;
            t10 = xm ? sr[b - 1]       : 0.0f;
            t11 =      sr[b];
            t12 = xp ? sr[b + 1]       : 0.0f;
            t20 = xm ? sr[b + 128 - 1] : 0.0f;
            t21 =      sr[b + 128];
            t22 = xp ? sr[b + 128 + 1] : 0.0f;
        }
#pragma unroll
        for (int v = 0; v < PV; ++v) {
            const float* wv = Wp + (c * PV + v) * 9;   // wave-uniform s_load
            float a = bp[c * PV + v];
            a += wv[0] * t00; a += wv[1] * t01; a += wv[2] * t02;
            a += wv[3] * t10; a += wv[4] * t11; a += wv[5] * t12;
            a += wv[6] * t20; a += wv[7] * t21; a += wv[8] * t22;
            const int kidx = c * PV + v;
            short h_, l_;
            bfsplit(a, h_, l_);
            p_hi[p * KP + kidx] = h_;
            p_lo[p * KP + kidx] = l_;
        }
    };
#pragma unroll
    for (int it = 0; it < 4; ++it) conv_site(it * NTHR + tid);  // ch 0..15
    if (tid < 768) conv_site(4 * NTHR + tid);                   // ch 16..18
    if (tid < 256) { p_hi[tid * KP + 95] = 0; p_lo[tid * KP + 95] = 0; }
    __syncthreads();

    // ---- phase B: mids = W1*p, 4-product split-bf16 MFMA ----
    f32x4v acc[2][4];
#pragma unroll
    for (int mt = 0; mt < 2; ++mt)
#pragma unroll
        for (int nt = 0; nt < 4; ++nt)
            acc[mt][nt] = (f32x4v){0.0f, 0.0f, 0.0f, 0.0f};

    const int pxb = wcol * 64;
#pragma unroll
    for (int nt = 0; nt < 4; ++nt) {
#pragma unroll
        for (int ks = 0; ks < 3; ++ks) {
            const short* bp_ = &p_hi[(pxb + nt * 16 + lw) * KP + ks * 32 + g8];
            bf16x8 bh = *(const bf16x8*)bp_;
            bf16x8 bl = *(const bf16x8*)(bp_ + 256 * KP);
            acc[0][nt] = __builtin_amdgcn_mfma_f32_16x16x32_bf16(ah[0][ks], bh, acc[0][nt], 0, 0, 0);
            acc[1][nt] = __builtin_amdgcn_mfma_f32_16x16x32_bf16(ah[1][ks], bh, acc[1][nt], 0, 0, 0);
            acc[0][nt] = __builtin_amdgcn_mfma_f32_16x16x32_bf16(ah[0][ks], bl, acc[0][nt], 0, 0, 0);
            acc[1][nt] = __builtin_amdgcn_mfma_f32_16x16x32_bf16(ah[1][ks], bl, acc[1][nt], 0, 0, 0);
            acc[0][nt] = __builtin_amdgcn_mfma_f32_16x16x32_bf16(al[0][ks], bh, acc[0][nt], 0, 0, 0);
            acc[1][nt] = __builtin_amdgcn_mfma_f32_16x16x32_bf16(al[1][ks], bh, acc[1][nt], 0, 0, 0);
            acc[0][nt] = __builtin_amdgcn_mfma_f32_16x16x32_bf16(al[0][ks], bl, acc[0][nt], 0, 0, 0);
            acc[1][nt] = __builtin_amdgcn_mfma_f32_16x16x32_bf16(al[1][ks], bl, acc[1][nt], 0, 0, 0);
        }
    }

    // h = leakyrelu(acc + b1)   (C layout: m = wrow*32+mt*16+g*4+reg)
#pragma unroll
    for (int mt = 0; mt < 2; ++mt) {
        f32x4v bq = *(const f32x4v*)&b1tab[wrow * 32 + mt * 16 + g * 4];
#pragma unroll
        for (int nt = 0; nt < 4; ++nt)
#pragma unroll
            for (int r = 0; r < 4; ++r) {
                float v = acc[mt][nt][r] + bq[r];
                acc[mt][nt][r] = (v >= 0.0f) ? v : 0.2f * v;
            }
    }
    __syncthreads();                               // all p reads done

    // ---- h_t hi pass + W2 frags (8 coalesced loads) ----
#pragma unroll
    for (int mt = 0; mt < 2; ++mt)
#pragma unroll
        for (int nt = 0; nt < 4; ++nt) {
            const int px = pxb + nt * 16 + lw;
            bf16x4 hv;
#pragma unroll
            for (int r = 0; r < 4; ++r) hv[r] = (short)f2bf_rtn(acc[mt][nt][r]);
            *(bf16x4*)&h_t[px * HT + wrow * 32 + mt * 16 + g * 4] = hv;
        }
    bf16x8 wh[4], wl[4];
    {
        const short* w2f = wscr + W1F_N;
#pragma unroll
        for (int ks = 0; ks < 4; ++ks) {
            const int base = ((ks * 2) * 64 + lane) * 8;
            wh[ks] = *(const bf16x8*)&w2f[base];
            wl[ks] = *(const bf16x8*)&w2f[base + 512];    // hl=1 chunk
        }
    }
    __syncthreads();

    // ---- W2 MFMA pass 1: (Wh + Wl) * h_hi ----
    f32x4v acc2 = (f32x4v){0.0f, 0.0f, 0.0f, 0.0f};
#pragma unroll
    for (int ks = 0; ks < 4; ++ks) {
        bf16x8 bh = *(const bf16x8*)&h_t[(w * 16 + lw) * HT + ks * 32 + g8];
        acc2 = __builtin_amdgcn_mfma_f32_16x16x32_bf16(wh[ks], bh, acc2, 0, 0, 0);
        acc2 = __builtin_amdgcn_mfma_f32_16x16x32_bf16(wl[ks], bh, acc2, 0, 0, 0);
    }
    __syncthreads();                               // pass-1 reads done

    // ---- h_t lo pass ----
#pragma unroll
    for (int mt = 0; mt < 2; ++mt)
#pragma unroll
        for (int nt = 0; nt < 4; ++nt) {
            const int px = pxb + nt * 16 + lw;
            bf16x4 lv;
#pragma unroll
            for (int r = 0; r < 4; ++r) {
                unsigned short hb = f2bf_rtn(acc[mt][nt][r]);
                lv[r] = (short)f2bf_rtn(acc[mt][nt][r] - bf2f(hb));
            }
            *(bf16x4*)&h_t[px * HT + wrow * 32 + mt * 16 + g * 4] = lv;
        }
    __syncthreads();

    // ---- W2 MFMA pass 2: (Wh + Wl) * h_lo ----
#pragma unroll
    for (int ks = 0; ks < 4; ++ks) {
        bf16x8 bl = *(const bf16x8*)&h_t[(w * 16 + lw) * HT + ks * 32 + g8];
        acc2 = __builtin_amdgcn_mfma_f32_16x16x32_bf16(wh[ks], bl, acc2, 0, 0, 0);
        acc2 = __builtin_amdgcn_mfma_f32_16x16x32_bf16(wl[ks], bl, acc2, 0, 0, 0);
    }

    // ---- epilogue: + b2 + residual(stile), store tmp_out ----
    {
        const int px = w * 16 + lw;                // wave w owns px-tile w
        const int gp = pixbase + px;
        float* tb = tmp_out + (size_t)n * ostride;
#pragma unroll
        for (int r = 0; r < 4; ++r) {
            const int o = g * 4 + r;               // C row = output channel
            float resid = stile[o * 512 + (1 + (px >> 7)) * 128 + (px & 127)];
            tb[(size_t)o * HW + gp] = acc2[r] + b2tab[o] + resid;
        }
    }
}

// ---------------------------------------------------------------------------
// final step 2: alive maxpool gate + sigmoid on channel 4 (tmp channel 1),
// writes state hidden region AND restores color channels (= x), which served
// as weight-frag scratch during the steps.
// ---------------------------------------------------------------------------
__global__ __launch_bounds__(256) void nca_step2(
        float* __restrict__ state,
        const float* __restrict__ tmp,
        const float* __restrict__ x) {
    int gid = blockIdx.x * 256 + threadIdx.x;      // 0 .. 65535
    int xx = gid & (WW - 1);
    int y = (gid >> 7) & (HH - 1);
    int n = gid >> 14;
    const int idx = y * WW + xx;

    const float* c4 = tmp + (size_t)n * HID * HW + 1 * HW;  // abs channel 4
    const bool ym = (y > 0), yp = (y < HH - 1);
    const bool xm = (xx > 0), xp = (xx < WW - 1);

    float mx = c4[idx];
    if (ym)       mx = fmaxf(mx, c4[idx - WW]);
    if (yp)       mx = fmaxf(mx, c4[idx + WW]);
    if (xm)       mx = fmaxf(mx, c4[idx - 1]);
    if (xp)       mx = fmaxf(mx, c4[idx + 1]);
    if (ym && xm) mx = fmaxf(mx, c4[idx - WW - 1]);
    if (ym && xp) mx = fmaxf(mx, c4[idx - WW + 1]);
    if (yp && xm) mx = fmaxf(mx, c4[idx + WW - 1]);
    if (yp && xp) mx = fmaxf(mx, c4[idx + WW + 1]);

    float alive = (mx > 0.0f) ? 1.0f : 0.0f;

    float* sb = state + (size_t)n * CST * HW + NC * HW + idx;
    const float* tb = tmp + (size_t)n * HID * HW + idx;
#pragma unroll
    for (int i = 0; i < HID; ++i) {
        float v = tb[i * HW] * alive;
        if (i == 1) v = 1.0f / (1.0f + expf(-v));   // sigmoid on abs ch 4
        sb[i * HW] = v;
    }
    // restore immutable color channels (scratch region during the steps)
    float* cb = state + (size_t)n * CST * HW + idx;
#pragma unroll
    for (int c = 0; c < NC; ++c)
        cb[(size_t)c * HW] = x[((size_t)n * NC + c) * HW + idx];
}

// ---------------------------------------------------------------------------
extern "C" void kernel_launch(void* const* d_in, const int* in_sizes, int n_in,
                              void* d_out, int out_size, void* d_ws, size_t ws_size,
                              hipStream_t stream) {
    const float* x  = (const float*)d_in[0];
    const float* Wp = (const float*)d_in[1];
    const float* bp = (const float*)d_in[2];
    const float* W1 = (const float*)d_in[3];
    const float* b1 = (const float*)d_in[4];
    const float* W2 = (const float*)d_in[5];
    const float* b2 = (const float*)d_in[6];
    // d_in[7] = steps (device scalar) -- fixed at 16 by setup_inputs

    float* state = (float*)d_out;                 // [4][19][128][128]
    float* ws    = (float*)d_ws;                  // [4][16][128][128] (4 MiB)

    // weight-frag scratch = image-0 color plane (57 KB of 196 KB; disjoint
    // from all hidden-channel regions; colors restored by nca_step2)
    short* wscr = (short*)state;

    float* bufA = state + (size_t)NC * HW;        // hidden region of state
    const long strideA = (long)CST * HW;
    float* bufB = ws;
    const long strideB = (long)HID * HW;

    nca_wprep<<<1, 1024, 0, stream>>>(wscr, W1, W2);

    const int blocks1 = (NN * HW) / TPX;          // 256 blocks x 1024 threads
    for (int s = 0; s < STEPS; ++s) {
        const float* tin;  long sin;
        float*       tout; long sout;
        if ((s & 1) == 0) { tin = bufB; sin = strideB; tout = bufA; sout = strideA; }
        else              { tin = bufA; sin = strideA; tout = bufB; sout = strideB; }
        nca_fused<<<blocks1, NTHR, 0, stream>>>(tin, sin, tout, sout,
                                                x, wscr, Wp, bp, b1, b2,
                                                (s == 0) ? 1 : 0);
    }
    // T15 is in bufB (ws); final gate+sigmoid -> state hidden, colors = x
    nca_step2<<<(NN * HW) / 256, 256, 0, stream>>>(state, ws, x);
}